// Round 1
// baseline (82.436 us; speedup 1.0000x reference)
//
#include <hip/hip_runtime.h>
#include <math.h>

typedef _Float16 half8 __attribute__((ext_vector_type(8)));
typedef float    f32x4 __attribute__((ext_vector_type(4)));

#define NPTS 1024
#define KMAX 64
#define R2   0.0225f
#define GRPS 4      // parallel point-groups per block (256 threads each)
#define REPS 2      // sequential points per group -> 8 points per block

// v2: anti-dispatch-trickle restructure.
// Counters showed avg wave lifetime ~1us but only ~0.24 waves/CU resident:
// 2048 tiny workgroups trickled through at ~28 WG/us. Consolidate to 256
// workgroups of 1024 threads: 4 parallel point-groups (each the old 4-wave
// per-point pipeline, private LDS slice) x 2 sequential points. Weights are
// loaded/unpacked and the zero-diag const MFMA computed ONCE per block.
// Inner per-point pipeline is byte-identical to the verified v1 kernel.
__global__ __launch_bounds__(1024, 4) void point_encoder_kernel(
    const float* __restrict__ xg,
    const float* __restrict__ W1g,
    const float* __restrict__ b1g,
    const float* __restrict__ W2g,
    const float* __restrict__ b2g,
    float* __restrict__ outg)
{
    __shared__ float nb[GRPS][KMAX * 3];   // per-group compacted rel coords
    __shared__ int   scnt[GRPS];

    const int tid  = threadIdx.x;
    const int grp  = tid >> 8;       // point-group 0..3
    const int t    = tid & 255;      // thread-in-group
    const int nt   = t >> 6;         // wave-in-group == o-tile id
    const int lane = tid & 63;
    const int kl   = lane & 15;      // A: m = k-slot ; B/C: n = o_local
    const int quad = lane >> 4;      // K-group: c = quad*8 + j

    // ---- weight loads + unpack: ONCE per block (was once per point) ----
    const int o = nt * 16 + kl;
    const f32x4 w2a = *(const f32x4*)(W2g + o * 32 + quad * 8);
    const f32x4 w2b = *(const f32x4*)(W2g + o * 32 + quad * 8 + 4);
    const float b2v = b2g[o];
    f32x4 w1raw[6];                  // W1 rows quad*8 .. quad*8+7 (stride 3)
    #pragma unroll
    for (int j = 0; j < 6; ++j)
        w1raw[j] = *(const f32x4*)(W1g + quad * 24 + j * 4);
    const f32x4 b1a = *(const f32x4*)(b1g + quad * 8);
    const f32x4 b1b = *(const f32x4*)(b1g + quad * 8 + 4);

    half8 Bf;                        // B[k=c][n=o]: lane holds W2[o][quad*8+j]
    #pragma unroll
    for (int j = 0; j < 4; ++j) {
        Bf[j]     = (_Float16)w2a[j];
        Bf[j + 4] = (_Float16)w2b[j];
    }
    float w1x[8], w1y[8], w1z[8], b1r[8];
    #pragma unroll
    for (int j = 0; j < 8; ++j) {
        w1x[j] = w1raw[(j*3    ) >> 2][(j*3    ) & 3];
        w1y[j] = w1raw[(j*3 + 1) >> 2][(j*3 + 1) & 3];
        w1z[j] = w1raw[(j*3 + 2) >> 2][(j*3 + 2) & 3];
        b1r[j] = (j < 4) ? b1a[j] : b1b[j - 4];
    }

    // ---- zero-diag const term (8 of 24 rotations): A = relu(b1) ----
    half8 Ac;
    #pragma unroll
    for (int j = 0; j < 8; ++j) Ac[j] = (_Float16)fmaxf(b1r[j], 0.f);
    f32x4 Cc = {0.f, 0.f, 0.f, 0.f};
    Cc = __builtin_amdgcn_mfma_f32_16x16x32_f16(Ac, Bf, Cc, 0, 0, 0);
    const float cbase = 8.f * fmaxf(Cc[0] + b2v, 0.f);

    for (int rep = 0; rep < REPS; ++rep) {
        // 8 consecutive points per block; NPTS % 8 == 0 so a block never
        // straddles the batch boundary. Requires total % (GRPS*REPS) == 0.
        const int pt = blockIdx.x * (GRPS * REPS) + rep * GRPS + grp;
        const int b  = pt >> 10;               // NPTS = 1024
        const int n  = pt & (NPTS - 1);

        __syncthreads();                       // WAR: prev rep's compute read nb
        if (t < KMAX * 3) nb[grp][t] = 0.f;    // zero-pad: h1=relu(b1)=self value,
        if (t == 0)       scnt[grp] = 0;       // can never change the max
        __syncthreads();

        // ---- in-ball scan: wave nt covers support [nt*256, nt*256+256) ----
        const float* xb = xg + b * NPTS * 3;
        const float qx = xb[n*3+0], qy = xb[n*3+1], qz = xb[n*3+2];
        #pragma unroll
        for (int it = 0; it < 4; ++it) {
            const int idx = nt * 256 + it * 64 + lane;
            const float dx = xb[idx*3+0] - qx;
            const float dy = xb[idx*3+1] - qy;
            const float dz = xb[idx*3+2] - qz;
            const float d2 = dx*dx + dy*dy + dz*dz;
            const bool pred = (d2 <= R2);
            const unsigned long long mask = __ballot(pred);
            const int cit = __popcll(mask);
            int base0 = 0;
            if (lane == 0 && cit) base0 = atomicAdd(&scnt[grp], cit);
            base0 = __shfl(base0, 0, 64);
            const int pos = base0 + __popcll(mask & ((1ull << lane) - 1ull));
            if (pred && pos < KMAX) {
                nb[grp][pos*3+0] = dx;
                nb[grp][pos*3+1] = dy;
                nb[grp][pos*3+2] = dz;
            }
        }
        __syncthreads();
        int cn = scnt[grp]; if (cn > KMAX) cn = KMAX;  // self (d2=0) always present
        const int ntiles = (cn + 15) >> 4;             // 1..4, typically 1-2

        float acc = cbase;
        float mv[10];
        #pragma unroll
        for (int i = 0; i < 10; ++i) mv[i] = -INFINITY;

        for (int mt = 0; mt < ntiles; ++mt) {
            const int k = mt * 16 + kl;
            const float gx = nb[grp][k*3+0];
            const float gy = nb[grp][k*3+1];
            const float gz = nb[grp][k*3+2];
            half8 A[10];
            #pragma unroll
            for (int j = 0; j < 8; ++j) {
                const float tx = w1x[j] * gx;
                const float ty = w1y[j] * gy;
                const float tz = w1z[j] * gz;
                const float pxy = tx + ty, mxy = tx - ty;
                const float bpz = b1r[j] + tz, bmz = b1r[j] - tz;
                A[0][j] = (_Float16)fmaxf(bpz + pxy, 0.f);   // ( 1, 1, 1)
                A[1][j] = (_Float16)fmaxf(bmz + mxy, 0.f);   // ( 1,-1,-1)
                A[2][j] = (_Float16)fmaxf(bmz - mxy, 0.f);   // (-1, 1,-1)
                A[3][j] = (_Float16)fmaxf(bpz - pxy, 0.f);   // (-1,-1, 1)
                A[4][j] = (_Float16)fmaxf(b1r[j] + tx, 0.f); // ( 1, 0, 0)
                A[5][j] = (_Float16)fmaxf(b1r[j] - tx, 0.f); // (-1, 0, 0)
                A[6][j] = (_Float16)fmaxf(b1r[j] + ty, 0.f); // ( 0, 1, 0)
                A[7][j] = (_Float16)fmaxf(b1r[j] - ty, 0.f); // ( 0,-1, 0)
                A[8][j] = (_Float16)fmaxf(bpz, 0.f);         // ( 0, 0, 1)
                A[9][j] = (_Float16)fmaxf(bmz, 0.f);         // ( 0, 0,-1)
            }
            #pragma unroll
            for (int i = 0; i < 10; ++i) {
                f32x4 C = {0.f, 0.f, 0.f, 0.f};
                C = __builtin_amdgcn_mfma_f32_16x16x32_f16(A[i], Bf, C, 0, 0, 0);
                mv[i] = fmaxf(mv[i], fmaxf(fmaxf(C[0], C[1]), fmaxf(C[2], C[3])));
            }
        }

        // ---- cross-quad max, bias, relu, weighted sum; direct store ----
        #pragma unroll
        for (int i = 0; i < 10; ++i) {
            float r = mv[i];
            r = fmaxf(r, __shfl_xor(r, 16, 64));
            r = fmaxf(r, __shfl_xor(r, 32, 64));
            acc += ((i < 4) ? 1.f : 2.f) * fmaxf(r + b2v, 0.f);
        }
        if (quad == 0)
            outg[(size_t)b * (64 * NPTS) + (size_t)o * NPTS + n] = acc * (1.f / 24.f);
    }
}

extern "C" void kernel_launch(void* const* d_in, const int* in_sizes, int n_in,
                              void* d_out, int out_size, void* d_ws, size_t ws_size,
                              hipStream_t stream) {
    const float* x  = (const float*)d_in[0];
    const float* W1 = (const float*)d_in[1];
    const float* b1 = (const float*)d_in[2];
    const float* W2 = (const float*)d_in[3];
    const float* b2 = (const float*)d_in[4];
    float* out = (float*)d_out;

    const int total  = in_sizes[0] / 3;            // B*N = 2048 points
    const int blocks = total / (GRPS * REPS);      // 256 workgroups, 1 per CU
    point_encoder_kernel<<<blocks, 1024, 0, stream>>>(x, W1, b1, W2, b2, out);
}

// Round 2
// 73.699 us; speedup vs baseline: 1.1185x; 1.1185x over previous
//
#include <hip/hip_runtime.h>
#include <math.h>

typedef _Float16 half8 __attribute__((ext_vector_type(8)));
typedef float    f32x4 __attribute__((ext_vector_type(4)));

#define NPTS 1024
#define KMAX 64
#define R2   0.0225f

// v3: revert to the verified v1 structure (2048 blocks x 256 threads).
// Round-1 evidence: consolidated 256x1024 launch made the PROFILED dispatch
// >=3x faster (<40us, dropped out of rocprof top-5) yet bench dur_us rose
// 74.5 -> 82.4. Only consistent with dur_us = fixed harness floor (~70us of
// re-poison fills/memsets in the timed graph) + real kernel time (v1 ~2-5us,
// v2 ~10-13us from 1-block/CU lockstep serialization). So: minimize REAL
// kernel time = v1's fully-parallel one-generation launch (8 blocks/CU,
// 32 waves/CU resident at once).
// Delta vs v1: LDS zero-fill of nb[] removed; A-build predicates k<cn
// instead (identical semantics: padding slots contributed exact zeros).
__global__ __launch_bounds__(256, 4) void point_encoder_kernel(
    const float* __restrict__ xg,
    const float* __restrict__ W1g,
    const float* __restrict__ b1g,
    const float* __restrict__ W2g,
    const float* __restrict__ b2g,
    float* __restrict__ outg)
{
    __shared__ float nb[KMAX * 3];   // compacted in-ball rel coords (shared)
    __shared__ int   cnt;

    const int tid  = threadIdx.x;
    const int nt   = tid >> 6;       // wave id == o-tile id
    const int lane = tid & 63;
    const int kl   = lane & 15;      // A: m = k-slot ; B/C: n = o_local
    const int quad = lane >> 4;      // K-group: c = quad*8 + j

    const int b = blockIdx.x >> 10;  // NPTS = 1024
    const int n = blockIdx.x & (NPTS - 1);

    // ---- issue all weight loads up front (consumed only after the scan) ----
    const int o = nt * 16 + kl;
    const f32x4 w2a = *(const f32x4*)(W2g + o * 32 + quad * 8);
    const f32x4 w2b = *(const f32x4*)(W2g + o * 32 + quad * 8 + 4);
    const float b2v = b2g[o];
    f32x4 w1raw[6];                  // W1 rows quad*8 .. quad*8+7 (stride 3)
    #pragma unroll
    for (int j = 0; j < 6; ++j)
        w1raw[j] = *(const f32x4*)(W1g + quad * 24 + j * 4);
    const f32x4 b1a = *(const f32x4*)(b1g + quad * 8);
    const f32x4 b1b = *(const f32x4*)(b1g + quad * 8 + 4);

    if (tid == 0) cnt = 0;
    __syncthreads();

    // ---- in-ball scan: wave nt covers support points [nt*256, nt*256+256) ----
    const float* xb = xg + b * NPTS * 3;
    const float qx = xb[n*3+0], qy = xb[n*3+1], qz = xb[n*3+2];
    #pragma unroll
    for (int it = 0; it < 4; ++it) {
        const int idx = nt * 256 + it * 64 + lane;
        const float dx = xb[idx*3+0] - qx;
        const float dy = xb[idx*3+1] - qy;
        const float dz = xb[idx*3+2] - qz;
        const float d2 = dx*dx + dy*dy + dz*dz;
        const bool pred = (d2 <= R2);
        const unsigned long long mask = __ballot(pred);
        const int cit = __popcll(mask);
        int base0 = 0;
        if (lane == 0 && cit) base0 = atomicAdd(&cnt, cit);
        base0 = __shfl(base0, 0, 64);
        const int pos = base0 + __popcll(mask & ((1ull << lane) - 1ull));
        if (pred && pos < KMAX) {
            nb[pos*3+0] = dx; nb[pos*3+1] = dy; nb[pos*3+2] = dz;
        }
    }
    __syncthreads();
    int cn = cnt; if (cn > KMAX) cn = KMAX;   // self (d2=0) always present
    const int ntiles = (cn + 15) >> 4;        // 1..4, typically 1-2

    // ---- unpack register-resident weights into fragments ----
    half8 Bf;                        // B[k=c][n=o]: lane holds W2[o][quad*8+j]
    #pragma unroll
    for (int j = 0; j < 4; ++j) {
        Bf[j]     = (_Float16)w2a[j];
        Bf[j + 4] = (_Float16)w2b[j];
    }
    float w1x[8], w1y[8], w1z[8], b1r[8];
    #pragma unroll
    for (int j = 0; j < 8; ++j) {
        w1x[j] = w1raw[(j*3    ) >> 2][(j*3    ) & 3];
        w1y[j] = w1raw[(j*3 + 1) >> 2][(j*3 + 1) & 3];
        w1z[j] = w1raw[(j*3 + 2) >> 2][(j*3 + 2) & 3];
        b1r[j] = (j < 4) ? b1a[j] : b1b[j - 4];
    }

    // ---- zero-diag const term (8 of 24 rotations): A = relu(b1) ----
    // all A rows identical -> all C rows identical -> no reduce needed
    half8 Ac;
    #pragma unroll
    for (int j = 0; j < 8; ++j) Ac[j] = (_Float16)fmaxf(b1r[j], 0.f);
    f32x4 Cc = {0.f, 0.f, 0.f, 0.f};
    Cc = __builtin_amdgcn_mfma_f32_16x16x32_f16(Ac, Bf, Cc, 0, 0, 0);
    float acc = 8.f * fmaxf(Cc[0] + b2v, 0.f);

    // ---- neighbor tiles: all 10 diags x this wave's o-tile ----
    float mv[10];
    #pragma unroll
    for (int i = 0; i < 10; ++i) mv[i] = -INFINITY;

    for (int mt = 0; mt < ntiles; ++mt) {
        const int k = mt * 16 + kl;
        const bool kv = (k < cn);   // slots >= cn behave as zero-padding
        const float gx = kv ? nb[k*3+0] : 0.f;
        const float gy = kv ? nb[k*3+1] : 0.f;
        const float gz = kv ? nb[k*3+2] : 0.f;
        half8 A[10];
        #pragma unroll
        for (int j = 0; j < 8; ++j) {
            const float tx = w1x[j] * gx;
            const float ty = w1y[j] * gy;
            const float tz = w1z[j] * gz;
            const float pxy = tx + ty, mxy = tx - ty;
            const float bpz = b1r[j] + tz, bmz = b1r[j] - tz;
            A[0][j] = (_Float16)fmaxf(bpz + pxy, 0.f);   // ( 1, 1, 1)
            A[1][j] = (_Float16)fmaxf(bmz + mxy, 0.f);   // ( 1,-1,-1)
            A[2][j] = (_Float16)fmaxf(bmz - mxy, 0.f);   // (-1, 1,-1)
            A[3][j] = (_Float16)fmaxf(bpz - pxy, 0.f);   // (-1,-1, 1)
            A[4][j] = (_Float16)fmaxf(b1r[j] + tx, 0.f); // ( 1, 0, 0)
            A[5][j] = (_Float16)fmaxf(b1r[j] - tx, 0.f); // (-1, 0, 0)
            A[6][j] = (_Float16)fmaxf(b1r[j] + ty, 0.f); // ( 0, 1, 0)
            A[7][j] = (_Float16)fmaxf(b1r[j] - ty, 0.f); // ( 0,-1, 0)
            A[8][j] = (_Float16)fmaxf(bpz, 0.f);         // ( 0, 0, 1)
            A[9][j] = (_Float16)fmaxf(bmz, 0.f);         // ( 0, 0,-1)
        }
        #pragma unroll
        for (int i = 0; i < 10; ++i) {
            f32x4 C = {0.f, 0.f, 0.f, 0.f};
            C = __builtin_amdgcn_mfma_f32_16x16x32_f16(A[i], Bf, C, 0, 0, 0);
            mv[i] = fmaxf(mv[i], fmaxf(fmaxf(C[0], C[1]), fmaxf(C[2], C[3])));
        }
    }

    // ---- cross-quad max, bias, relu, weighted sum; direct store ----
    #pragma unroll
    for (int i = 0; i < 10; ++i) {
        float r = mv[i];
        r = fmaxf(r, __shfl_xor(r, 16, 64));
        r = fmaxf(r, __shfl_xor(r, 32, 64));
        acc += ((i < 4) ? 1.f : 2.f) * fmaxf(r + b2v, 0.f);
    }
    if (quad == 0)
        outg[(size_t)b * (64 * NPTS) + (size_t)o * NPTS + n] = acc * (1.f / 24.f);
}

extern "C" void kernel_launch(void* const* d_in, const int* in_sizes, int n_in,
                              void* d_out, int out_size, void* d_ws, size_t ws_size,
                              hipStream_t stream) {
    const float* x  = (const float*)d_in[0];
    const float* W1 = (const float*)d_in[1];
    const float* b1 = (const float*)d_in[2];
    const float* W2 = (const float*)d_in[3];
    const float* b2 = (const float*)d_in[4];
    float* out = (float*)d_out;

    const int total = in_sizes[0] / 3;   // B*N = 2048 points = blocks
    point_encoder_kernel<<<total, 256, 0, stream>>>(x, W1, b1, W2, b2, out);
}